// Round 11
// baseline (244.227 us; speedup 1.0000x reference)
//
#include <hip/hip_runtime.h>
#include <hip/hip_bf16.h>
#include <stdint.h>

// N=4096, IN=512, OUT=64, H=8. Inputs (fp32): x, adj(int32), W, a1, a2. Output fp32[N, H*OUT].
// 2-kernel pipeline:
//   K1 fused_prep: sections [pack_adj | wh(+EF fused)]   K2 gat2: softmax+PV+normalize
// ws: bitsT 2M@0 | WhhT 4M@2M | EF1 256K@6M | EF2 256K@6.25M   => 6.5 MB

constexpr int N_ = 4096, IN_ = 512, OUT_ = 64, H_ = 8;
constexpr float ALPHA_ = 0.2f;
constexpr int PACKB_ = (N_ * N_) / 256;   // 65536 pack blocks

typedef __attribute__((ext_vector_type(8))) short short8;
typedef __attribute__((ext_vector_type(4))) float f32x4;

__device__ __forceinline__ uint32_t pkbf(float a, float b) {
    union { __hip_bfloat162 h2; uint32_t u; } c;
    c.h2 = __float22bfloat162_rn(make_float2(a, b));
    return c.u;
}
__device__ __forceinline__ short8 ld_bf8(const uint16_t* ptr) {
    union { uint4 v; short8 s; } u;
    u.v = *(const uint4*)ptr;
    return u.s;
}

// ---------- K1: section A = pack adj -> bitsT[c*N+n]; section B = Wh GEMM + EF + WhhT
__global__ __launch_bounds__(256) void fused_prep(const int* __restrict__ adj,
                                                  const float* __restrict__ x,
                                                  const float* __restrict__ W,
                                                  const float* __restrict__ a1,
                                                  const float* __restrict__ a2,
                                                  unsigned long long* __restrict__ bitsT,
                                                  uint16_t* __restrict__ WhhT,
                                                  float2* __restrict__ EF1,
                                                  float2* __restrict__ EF2) {
    __shared__ float Ws[32 * 68];
    const int bx = blockIdx.x, t = threadIdx.x;

    if (bx < PACKB_) {   // ---- pack_adj ----
        size_t g = (size_t)bx * 256 + t;            // g = n*4096 + m
        int v = adj[g];
        unsigned long long m = __ballot(v != 0);
        if ((t & 63) == 0) {
            int n = (int)(g >> 12);
            int c = (int)((g >> 6) & 63);
            bitsT[(size_t)c * N_ + n] = m;
        }
        return;
    }
    // ---- wh: 32 rows x 64 cols per block; W read strided fp32, hi/lo 3-MFMA ----
    const int bb = bx - PACKB_;
    const int h  = bb & 7;                          // head->XCD swizzle
    const int n0 = (bb >> 3) * 32;
    const int l = t & 63, w = t >> 6, p = l & 15, q = l >> 4;
    const int r0 = (w & 1) * 16;
    const int c0 = (w >> 1) * 32;

    f32x4 acc0 = (f32x4){0.f, 0.f, 0.f, 0.f};
    f32x4 acc1 = (f32x4){0.f, 0.f, 0.f, 0.f};
    const float* gx = x + (size_t)(n0 + r0 + p) * IN_ + q * 8;
    const float* gW = W + (size_t)h * IN_ * OUT_ + q * 8 * OUT_;

#pragma unroll 2
    for (int ks = 0; ks < 16; ks++) {
        const int off = ks * 32;
        float4 xa = *(const float4*)(gx + off);
        float4 xb = *(const float4*)(gx + off + 4);
        float va[8] = {xa.x, xa.y, xa.z, xa.w, xb.x, xb.y, xb.z, xb.w};
        union { short8 s; uint32_t u[4]; } ah, al;
#pragma unroll
        for (int i = 0; i < 4; i++) {
            ah.u[i] = pkbf(va[2 * i], va[2 * i + 1]);
            float ha = __uint_as_float(ah.u[i] << 16);
            float hb = __uint_as_float(ah.u[i] & 0xffff0000u);
            al.u[i] = pkbf(va[2 * i] - ha, va[2 * i + 1] - hb);
        }
        const float* wp = gW + (size_t)off * OUT_;
        float w0[8], w1[8];
#pragma unroll
        for (int j = 0; j < 8; j++) {
            w0[j] = wp[j * OUT_ + c0 + p];
            w1[j] = wp[j * OUT_ + c0 + 16 + p];
        }
        union { short8 s; uint32_t u[4]; } bh0, bl0, bh1, bl1;
#pragma unroll
        for (int i = 0; i < 4; i++) {
            bh0.u[i] = pkbf(w0[2 * i], w0[2 * i + 1]);
            float ha = __uint_as_float(bh0.u[i] << 16);
            float hb = __uint_as_float(bh0.u[i] & 0xffff0000u);
            bl0.u[i] = pkbf(w0[2 * i] - ha, w0[2 * i + 1] - hb);
            bh1.u[i] = pkbf(w1[2 * i], w1[2 * i + 1]);
            float hc = __uint_as_float(bh1.u[i] << 16);
            float hd = __uint_as_float(bh1.u[i] & 0xffff0000u);
            bl1.u[i] = pkbf(w1[2 * i] - hc, w1[2 * i + 1] - hd);
        }
        acc0 = __builtin_amdgcn_mfma_f32_16x16x32_bf16(ah.s, bh0.s, acc0, 0, 0, 0);
        acc0 = __builtin_amdgcn_mfma_f32_16x16x32_bf16(al.s, bh0.s, acc0, 0, 0, 0);
        acc0 = __builtin_amdgcn_mfma_f32_16x16x32_bf16(ah.s, bl0.s, acc0, 0, 0, 0);
        acc1 = __builtin_amdgcn_mfma_f32_16x16x32_bf16(ah.s, bh1.s, acc1, 0, 0, 0);
        acc1 = __builtin_amdgcn_mfma_f32_16x16x32_bf16(al.s, bh1.s, acc1, 0, 0, 0);
        acc1 = __builtin_amdgcn_mfma_f32_16x16x32_bf16(ah.s, bl1.s, acc1, 0, 0, 0);
    }
    // D[m][o]: row = r0 + q*4+reg, col = c0 (+16) + p
#pragma unroll
    for (int reg = 0; reg < 4; reg++) {
        Ws[(r0 + q * 4 + reg) * 68 + c0 + p]      = acc0[reg];
        Ws[(r0 + q * 4 + reg) * 68 + c0 + 16 + p] = acc1[reg];
    }
    __syncthreads();
    if (t < 128) {   // f1/f2 dots -> EF vectors (4 threads per row)
        int r = t >> 2, og = (t & 3) * 16;
        float s1 = 0.f, s2 = 0.f;
#pragma unroll
        for (int j = 0; j < 4; j++) {
            float4 wv = *(const float4*)&Ws[r * 68 + og + j * 4];
            float4 av = *(const float4*)(a1 + h * OUT_ + og + j * 4);
            float4 bv = *(const float4*)(a2 + h * OUT_ + og + j * 4);
            s1 += wv.x * av.x + wv.y * av.y + wv.z * av.z + wv.w * av.w;
            s2 += wv.x * bv.x + wv.y * bv.y + wv.z * bv.z + wv.w * bv.w;
        }
        s1 += __shfl_xor(s1, 1, 64); s1 += __shfl_xor(s1, 2, 64);
        s2 += __shfl_xor(s2, 1, 64); s2 += __shfl_xor(s2, 2, 64);
        if ((t & 3) == 0) {
            EF1[(size_t)h * N_ + n0 + r] = make_float2(__expf(s1), __expf(ALPHA_ * s1));
            EF2[(size_t)h * N_ + n0 + r] = make_float2(__expf(s2), __expf(ALPHA_ * s2));
        }
    }
    {   // WhhT bf16 [h][o][n]
        int o = t >> 2, ns = (t & 3) * 8;
        uint32_t ph[4];
#pragma unroll
        for (int i = 0; i < 4; i++)
            ph[i] = pkbf(Ws[(ns + 2 * i) * 68 + o], Ws[(ns + 2 * i + 1) * 68 + o]);
        *(uint4*)&WhhT[((size_t)h * OUT_ + o) * N_ + n0 + ns] = make_uint4(ph[0], ph[1], ph[2], ph[3]);
    }
}

// ---------- K2: 32 rows x 1 head per block (2 waves). Double-buffered Bh,
// factored exp, L via ones-MFMA, normalization fused. Grid 1024 1-D, h = bx&7.
__global__ __launch_bounds__(128) void gat2(const unsigned long long* __restrict__ bitsT,
                                            const uint16_t* __restrict__ WhhT,
                                            const float2* __restrict__ EF1,
                                            const float2* __restrict__ EF2,
                                            float* __restrict__ out) {
    __shared__ __align__(16) uint16_t Bh[2][64 * 72];   // 18432 B
    const int bx = blockIdx.x, t = threadIdx.x;
    const int h = bx & 7;                              // head->XCD swizzle (L2 locality)
    const int n0 = (bx >> 3) * 32;
    const int l = t & 63, wv = t >> 6, p = l & 15, q = l >> 4;
    const int sr = t >> 1, sc = (t & 1) * 32;
    const int row = wv * 16 + p;                       // lane's P row (A-frag m)

    const float2 ef1 = EF1[(size_t)h * N_ + n0 + row];
    const float E1v = ef1.x, F1v = ef1.y;
    const float2* efb = EF2 + (size_t)h * N_ + q * 8;
    const unsigned long long* bp = bitsT + n0 + row;
    const uint16_t* gb = WhhT + ((size_t)h * OUT_ + sr) * N_ + sc;

    short8 ones;
    {
        union { short8 s; uint32_t u[4]; } o;
        o.u[0] = o.u[1] = o.u[2] = o.u[3] = 0x3f803f80u;
        ones = o.s;
    }

    f32x4 acc[4], accL;
#pragma unroll
    for (int ct = 0; ct < 4; ct++) acc[ct] = (f32x4){0.f, 0.f, 0.f, 0.f};
    accL = (f32x4){0.f, 0.f, 0.f, 0.f};

    // prologue: chunk 0 -> regs -> LDS[0]
    {
        uint4 pb0 = *(const uint4*)(gb);
        uint4 pb1 = *(const uint4*)(gb + 8);
        uint4 pb2 = *(const uint4*)(gb + 16);
        uint4 pb3 = *(const uint4*)(gb + 24);
        *(uint4*)&Bh[0][sr * 72 + sc]      = pb0;
        *(uint4*)&Bh[0][sr * 72 + sc + 8]  = pb1;
        *(uint4*)&Bh[0][sr * 72 + sc + 16] = pb2;
        *(uint4*)&Bh[0][sr * 72 + sc + 24] = pb3;
    }
    unsigned long long word = bp[0];

    for (int cc = 0; cc < 64; cc++) {
        const int cur = cc & 1;
        const int m0 = cc * 64;
        uint4 nb0, nb1, nb2, nb3;
        unsigned long long nword = 0;
        if (cc + 1 < 64) {   // next-chunk loads fly during the barrier
            nb0 = *(const uint4*)(gb + m0 + 64);
            nb1 = *(const uint4*)(gb + m0 + 64 + 8);
            nb2 = *(const uint4*)(gb + m0 + 64 + 16);
            nb3 = *(const uint4*)(gb + m0 + 64 + 24);
            nword = bp[(size_t)(cc + 1) * N_];
        }
        __syncthreads();     // LDS[cur] writes visible; prior reads of LDS[cur^1] done
        union { short8 s; uint32_t u[4]; } af[2];
#pragma unroll
        for (int k0 = 0; k0 < 2; k0++) {
            const float4* ep = (const float4*)(efb + m0 + k0 * 32);
            float4 e0 = ep[0], e1 = ep[1], e2 = ep[2], e3 = ep[3];
            float ev[8] = {e0.x, e0.z, e1.x, e1.z, e2.x, e2.z, e3.x, e3.z};
            float fv[8] = {e0.y, e0.w, e1.y, e1.w, e2.y, e2.w, e3.y, e3.w};
            uint32_t bits8 = (uint32_t)(word >> (k0 * 32 + q * 8)) & 0xffu;
            float pv[8];
#pragma unroll
            for (int j = 0; j < 8; j++) {
                float m = fmaxf(E1v * ev[j], F1v * fv[j]);   // exp(leakyrelu(f1+f2))
                pv[j] = ((bits8 >> j) & 1u) ? m : 0.f;
            }
#pragma unroll
            for (int i = 0; i < 4; i++) af[k0].u[i] = pkbf(pv[2 * i], pv[2 * i + 1]);
        }
#pragma unroll
        for (int k0 = 0; k0 < 2; k0++) {
            short8 bb0 = ld_bf8(&Bh[cur][(0 * 16 + p) * 72 + q * 8 + k0 * 32]);
            short8 bb1 = ld_bf8(&Bh[cur][(1 * 16 + p) * 72 + q * 8 + k0 * 32]);
            short8 bb2 = ld_bf8(&Bh[cur][(2 * 16 + p) * 72 + q * 8 + k0 * 32]);
            short8 bb3 = ld_bf8(&Bh[cur][(3 * 16 + p) * 72 + q * 8 + k0 * 32]);
            accL   = __builtin_amdgcn_mfma_f32_16x16x32_bf16(af[k0].s, ones, accL, 0, 0, 0);
            acc[0] = __builtin_amdgcn_mfma_f32_16x16x32_bf16(af[k0].s, bb0, acc[0], 0, 0, 0);
            acc[1] = __builtin_amdgcn_mfma_f32_16x16x32_bf16(af[k0].s, bb1, acc[1], 0, 0, 0);
            acc[2] = __builtin_amdgcn_mfma_f32_16x16x32_bf16(af[k0].s, bb2, acc[2], 0, 0, 0);
            acc[3] = __builtin_amdgcn_mfma_f32_16x16x32_bf16(af[k0].s, bb3, acc[3], 0, 0, 0);
        }
        if (cc + 1 < 64) {
            *(uint4*)&Bh[cur ^ 1][sr * 72 + sc]      = nb0;
            *(uint4*)&Bh[cur ^ 1][sr * 72 + sc + 8]  = nb1;
            *(uint4*)&Bh[cur ^ 1][sr * 72 + sc + 16] = nb2;
            *(uint4*)&Bh[cur ^ 1][sr * 72 + sc + 24] = nb3;
            word = nword;
        }
    }
    // epilogue: normalize + store. C/D row = q*4+reg (within wave's 16), col = ct*16+p.
    float invL[4];
#pragma unroll
    for (int reg = 0; reg < 4; reg++) invL[reg] = 1.0f / accL[reg];
#pragma unroll
    for (int ct = 0; ct < 4; ct++)
#pragma unroll
        for (int reg = 0; reg < 4; reg++) {
            int rr = wv * 16 + q * 4 + reg;
            out[(size_t)(n0 + rr) * (H_ * OUT_) + h * OUT_ + ct * 16 + p] = acc[ct][reg] * invL[reg];
        }
}

extern "C" void kernel_launch(void* const* d_in, const int* in_sizes, int n_in,
                              void* d_out, int out_size, void* d_ws, size_t ws_size,
                              hipStream_t stream) {
    const float* x   = nullptr;
    const int*   adj = nullptr;
    const float* W   = nullptr;
    const float* a1  = nullptr;
    const float* a2  = nullptr;
    for (int i = 0; i < n_in; i++) {
        long long sz = in_sizes[i];
        if      (sz == (long long)N_ * IN_)        x   = (const float*)d_in[i];
        else if (sz == (long long)N_ * N_)         adj = (const int*)d_in[i];
        else if (sz == (long long)H_ * IN_ * OUT_) W   = (const float*)d_in[i];
        else if (sz == (long long)H_ * OUT_) {
            if (!a1) a1 = (const float*)d_in[i];
            else     a2 = (const float*)d_in[i];
        }
    }
    if (!x)   x   = (const float*)d_in[0];
    if (!adj) adj = (const int*)d_in[1];
    if (!W)   W   = (const float*)d_in[2];
    if (!a1)  a1  = (const float*)d_in[3];
    if (!a2)  a2  = (const float*)d_in[4];
    float* out = (float*)d_out;

    char* ws = (char*)d_ws;
    unsigned long long* bitsT = (unsigned long long*)ws;             // 2 MB @0
    uint16_t* WhhT = (uint16_t*)(ws + (2u << 20));                   // 4 MB
    float2* EF1    = (float2*)  (ws + (6u << 20));                   // 256 KB
    float2* EF2    = (float2*)  (ws + (6u << 20) + (256u << 10));    // 256 KB

    fused_prep<<<PACKB_ + (N_ / 32) * H_, 256, 0, stream>>>(adj, x, W, a1, a2,
                                                            bitsT, WhhT, EF1, EF2);
    gat2<<<(N_ / 32) * H_, 128, 0, stream>>>(bitsT, WhhT, EF1, EF2, out);
}

// Round 12
// 242.184 us; speedup vs baseline: 1.0084x; 1.0084x over previous
//
#include <hip/hip_runtime.h>
#include <hip/hip_bf16.h>
#include <stdint.h>

// N=4096, IN=512, OUT=64, H=8. Inputs (fp32): x, adj(int32), W, a1, a2. Output fp32[N, H*OUT].
// Pipeline: split_wT -> fused_prep[pack_adj | wh+EF] -> gat_main(zc=2) -> combine
// ws: bitsT 2M@0 | WhhT 4M@2M | WTh 512K@6M | WTl 512K@6.5M | EF1 256K@7M | EF2 256K@7.25M |
//     Lpart 512K@7.5M | opart 8M@8M  => 16 MB

constexpr int N_ = 4096, IN_ = 512, OUT_ = 64, H_ = 8;
constexpr float ALPHA_ = 0.2f;
constexpr int PACKB_ = (N_ * N_) / 256;   // 65536 pack blocks

typedef __attribute__((ext_vector_type(8))) short short8;
typedef __attribute__((ext_vector_type(4))) float f32x4;

__device__ __forceinline__ uint32_t pkbf(float a, float b) {
    union { __hip_bfloat162 h2; uint32_t u; } c;
    c.h2 = __float22bfloat162_rn(make_float2(a, b));
    return c.u;
}
__device__ __forceinline__ uint32_t rne_pack2(float a, float b, float& ra, float& rb) {
    uint32_t ua = __float_as_uint(a); ua += 0x7fffu + ((ua >> 16) & 1u); ua >>= 16;
    uint32_t ub = __float_as_uint(b); ub += 0x7fffu + ((ub >> 16) & 1u); ub >>= 16;
    ra = __uint_as_float(ua << 16);
    rb = __uint_as_float(ub << 16);
    return ua | (ub << 16);
}
__device__ __forceinline__ short8 ld_bf8(const uint16_t* ptr) {
    union { uint4 v; short8 s; } u;
    u.v = *(const uint4*)ptr;
    return u.s;
}

// ---------- W [h][k][o] fp32 -> WT hi/lo bf16 [h][o][k] (B-operand layout)
__global__ __launch_bounds__(256) void split_wT(const float* __restrict__ W,
                                                uint16_t* __restrict__ WTh,
                                                uint16_t* __restrict__ WTl) {
    __shared__ float T[64 * 68];
    const int t  = threadIdx.x;
    const int kb = blockIdx.x;   // 0..7
    const int h  = blockIdx.y;
    {
        int kk = t >> 2, os = (t & 3) * 16;
        const float* src = W + ((size_t)h * IN_ + kb * 64 + kk) * OUT_ + os;
#pragma unroll
        for (int j = 0; j < 4; j++)
            *(float4*)&T[kk * 68 + os + j * 4] = *(const float4*)(src + j * 4);
    }
    __syncthreads();
    int o = t >> 2, ks = (t & 3) * 16;
    uint32_t ph[8], pl[8];
#pragma unroll
    for (int i = 0; i < 8; i++) {
        float va = T[(ks + 2 * i) * 68 + o], vb = T[(ks + 2 * i + 1) * 68 + o];
        float h0, h1, d0, d1;
        ph[i] = rne_pack2(va, vb, h0, h1);
        pl[i] = rne_pack2(va - h0, vb - h1, d0, d1);
    }
    size_t dst = ((size_t)h * OUT_ + o) * IN_ + kb * 64 + ks;
    *(uint4*)&WTh[dst]     = make_uint4(ph[0], ph[1], ph[2], ph[3]);
    *(uint4*)&WTh[dst + 8] = make_uint4(ph[4], ph[5], ph[6], ph[7]);
    *(uint4*)&WTl[dst]     = make_uint4(pl[0], pl[1], pl[2], pl[3]);
    *(uint4*)&WTl[dst + 8] = make_uint4(pl[4], pl[5], pl[6], pl[7]);
}

// ---------- K1: section A = pack_adj; section B = Wh GEMM (vectorized WT) + EF + WhhT
__global__ __launch_bounds__(256) void fused_prep(const int* __restrict__ adj,
                                                  const float* __restrict__ x,
                                                  const uint16_t* __restrict__ WTh,
                                                  const uint16_t* __restrict__ WTl,
                                                  const float* __restrict__ a1,
                                                  const float* __restrict__ a2,
                                                  unsigned long long* __restrict__ bitsT,
                                                  uint16_t* __restrict__ WhhT,
                                                  float2* __restrict__ EF1,
                                                  float2* __restrict__ EF2) {
    __shared__ float Ws[32 * 68];
    const int bx = blockIdx.x, t = threadIdx.x;

    if (bx < PACKB_) {   // ---- pack_adj: bitsT[c*N+n], bit i = adj[n][c*64+i] ----
        size_t g = (size_t)bx * 256 + t;            // g = n*4096 + m
        int v = adj[g];
        unsigned long long m = __ballot(v != 0);
        if ((t & 63) == 0) {
            int n = (int)(g >> 12);
            int c = (int)((g >> 6) & 63);
            bitsT[(size_t)c * N_ + n] = m;
        }
        return;
    }
    // ---- wh: 32 rows x 64 cols per block (R10 wh_all structure) ----
    const int bb = bx - PACKB_;
    const int h  = bb & 7;
    const int n0 = (bb >> 3) * 32;
    const int l = t & 63, w = t >> 6, p = l & 15, q = l >> 4;
    const int r0 = (w & 1) * 16;
    const int c0 = (w >> 1) * 32;

    f32x4 acc0 = (f32x4){0.f, 0.f, 0.f, 0.f};
    f32x4 acc1 = (f32x4){0.f, 0.f, 0.f, 0.f};
    const float* gx = x + (size_t)(n0 + r0 + p) * IN_ + q * 8;
    const uint16_t* gbh0 = WTh + ((size_t)h * OUT_ + c0 + p) * IN_ + q * 8;
    const uint16_t* gbl0 = WTl + ((size_t)h * OUT_ + c0 + p) * IN_ + q * 8;
    const uint16_t* gbh1 = gbh0 + (size_t)16 * IN_;
    const uint16_t* gbl1 = gbl0 + (size_t)16 * IN_;

#pragma unroll 4
    for (int ks = 0; ks < 16; ks++) {
        const int off = ks * 32;
        float4 xa = *(const float4*)(gx + off);
        float4 xb = *(const float4*)(gx + off + 4);
        float va[8] = {xa.x, xa.y, xa.z, xa.w, xb.x, xb.y, xb.z, xb.w};
        union { short8 s; uint32_t u[4]; } ah, al;
#pragma unroll
        for (int i = 0; i < 4; i++) {
            ah.u[i] = pkbf(va[2 * i], va[2 * i + 1]);
            float ha = __uint_as_float(ah.u[i] << 16);
            float hb = __uint_as_float(ah.u[i] & 0xffff0000u);
            al.u[i] = pkbf(va[2 * i] - ha, va[2 * i + 1] - hb);
        }
        short8 bh0 = ld_bf8(gbh0 + off), bl0 = ld_bf8(gbl0 + off);
        short8 bh1 = ld_bf8(gbh1 + off), bl1 = ld_bf8(gbl1 + off);
        acc0 = __builtin_amdgcn_mfma_f32_16x16x32_bf16(ah.s, bh0, acc0, 0, 0, 0);
        acc0 = __builtin_amdgcn_mfma_f32_16x16x32_bf16(al.s, bh0, acc0, 0, 0, 0);
        acc0 = __builtin_amdgcn_mfma_f32_16x16x32_bf16(ah.s, bl0, acc0, 0, 0, 0);
        acc1 = __builtin_amdgcn_mfma_f32_16x16x32_bf16(ah.s, bh1, acc1, 0, 0, 0);
        acc1 = __builtin_amdgcn_mfma_f32_16x16x32_bf16(al.s, bh1, acc1, 0, 0, 0);
        acc1 = __builtin_amdgcn_mfma_f32_16x16x32_bf16(ah.s, bl1, acc1, 0, 0, 0);
    }
#pragma unroll
    for (int reg = 0; reg < 4; reg++) {
        Ws[(r0 + q * 4 + reg) * 68 + c0 + p]      = acc0[reg];
        Ws[(r0 + q * 4 + reg) * 68 + c0 + 16 + p] = acc1[reg];
    }
    __syncthreads();
    if (t < 128) {   // f1/f2 dots -> EF vectors (4 threads per row)
        int r = t >> 2, og = (t & 3) * 16;
        float s1 = 0.f, s2 = 0.f;
#pragma unroll
        for (int j = 0; j < 4; j++) {
            float4 wv = *(const float4*)&Ws[r * 68 + og + j * 4];
            float4 av = *(const float4*)(a1 + h * OUT_ + og + j * 4);
            float4 bv = *(const float4*)(a2 + h * OUT_ + og + j * 4);
            s1 += wv.x * av.x + wv.y * av.y + wv.z * av.z + wv.w * av.w;
            s2 += wv.x * bv.x + wv.y * bv.y + wv.z * bv.z + wv.w * bv.w;
        }
        s1 += __shfl_xor(s1, 1, 64); s1 += __shfl_xor(s1, 2, 64);
        s2 += __shfl_xor(s2, 1, 64); s2 += __shfl_xor(s2, 2, 64);
        if ((t & 3) == 0) {
            EF1[(size_t)h * N_ + n0 + r] = make_float2(__expf(s1), __expf(ALPHA_ * s1));
            EF2[(size_t)h * N_ + n0 + r] = make_float2(__expf(s2), __expf(ALPHA_ * s2));
        }
    }
    {   // WhhT bf16 [h][o][n]
        int o = t >> 2, ns = (t & 3) * 8;
        uint32_t ph[4];
#pragma unroll
        for (int i = 0; i < 4; i++)
            ph[i] = pkbf(Ws[(ns + 2 * i) * 68 + o], Ws[(ns + 2 * i + 1) * 68 + o]);
        *(uint4*)&WhhT[((size_t)h * OUT_ + o) * N_ + n0 + ns] = make_uint4(ph[0], ph[1], ph[2], ph[3]);
    }
}

// ---------- main: R10 structure (64 rows, 256 thr, zc=2) + 2-chunk-unrolled double buffer.
__global__ __launch_bounds__(256) void gat_main(const unsigned long long* __restrict__ bitsT,
                                                const uint16_t* __restrict__ WhhT,
                                                const float2* __restrict__ EF1,
                                                const float2* __restrict__ EF2,
                                                float* __restrict__ out,
                                                float* __restrict__ opart,
                                                float* __restrict__ Lpart) {
    __shared__ __align__(16) uint16_t Bh[2][2 * 64 * 72];   // 36864 B -> 4 blocks/CU
    const int t = threadIdx.x, h = blockIdx.y, z = blockIdx.z, n0 = blockIdx.x * 64;
    const int cbase = z * 32;                                // 32 chunks per z
    const int l = t & 63, w = t >> 6, p = l & 15, q = l >> 4;
    const int sr = t >> 2, sc = (t & 3) * 16;
    const int row = w * 16 + p;

    const float2 ef1 = EF1[(size_t)h * N_ + n0 + row];
    const float E1v = ef1.x, F1v = ef1.y;
    const float2* efb = EF2 + (size_t)h * N_ + q * 8;
    const unsigned long long* bp = bitsT + n0 + row;
    const uint16_t* gb = WhhT + ((size_t)h * OUT_ + sr) * N_ + sc;

    short8 ones;
    {
        union { short8 s; uint32_t u[4]; } o;
        o.u[0] = o.u[1] = o.u[2] = o.u[3] = 0x3f803f80u;
        ones = o.s;
    }

    f32x4 acc[4], accL;
#pragma unroll
    for (int ct = 0; ct < 4; ct++) acc[ct] = (f32x4){0.f, 0.f, 0.f, 0.f};
    accL = (f32x4){0.f, 0.f, 0.f, 0.f};

    unsigned long long wrd[2];
    // prologue: chunks cbase, cbase+1 -> LDS[0]
    {
        uint4 a0 = *(const uint4*)(gb + cbase * 64);
        uint4 a1v = *(const uint4*)(gb + cbase * 64 + 8);
        uint4 b0 = *(const uint4*)(gb + (cbase + 1) * 64);
        uint4 b1 = *(const uint4*)(gb + (cbase + 1) * 64 + 8);
        wrd[0] = bp[(size_t)cbase * N_];
        wrd[1] = bp[(size_t)(cbase + 1) * N_];
        *(uint4*)&Bh[0][sr * 72 + sc]                 = a0;
        *(uint4*)&Bh[0][sr * 72 + sc + 8]             = a1v;
        *(uint4*)&Bh[0][64 * 72 + sr * 72 + sc]       = b0;
        *(uint4*)&Bh[0][64 * 72 + sr * 72 + sc + 8]   = b1;
    }

    for (int it = 0; it < 16; it++) {
        const int cur = it & 1;
        const int c0ch = cbase + 2 * it;
        uint4 na0, na1, nb0, nb1;
        unsigned long long nw0 = 0, nw1 = 0;
        if (it + 1 < 16) {   // prefetch next 2 chunks; loads fly during the barrier
            na0 = *(const uint4*)(gb + (c0ch + 2) * 64);
            na1 = *(const uint4*)(gb + (c0ch + 2) * 64 + 8);
            nb0 = *(const uint4*)(gb + (c0ch + 3) * 64);
            nb1 = *(const uint4*)(gb + (c0ch + 3) * 64 + 8);
            nw0 = bp[(size_t)(c0ch + 2) * N_];
            nw1 = bp[(size_t)(c0ch + 3) * N_];
        }
        __syncthreads();     // LDS[cur] writes visible; prior reads of LDS[cur^1] done
#pragma unroll
        for (int sub = 0; sub < 2; sub++) {
            const int m0 = (c0ch + sub) * 64;
            const unsigned long long word = wrd[sub];
            const uint16_t* Bsub = &Bh[cur][sub * 64 * 72];
            union { short8 s; uint32_t u[4]; } af[2];
#pragma unroll
            for (int k0 = 0; k0 < 2; k0++) {
                const float4* ep = (const float4*)(efb + m0 + k0 * 32);
                float4 e0 = ep[0], e1 = ep[1], e2 = ep[2], e3 = ep[3];
                float ev[8] = {e0.x, e0.z, e1.x, e1.z, e2.x, e2.z, e3.x, e3.z};
                float fv[8] = {e0.y, e0.w, e1.y, e1.w, e2.y, e2.w, e3.y, e3.w};
                uint32_t bits8 = (uint32_t)(word >> (k0 * 32 + q * 8)) & 0xffu;
                float pv[8];
#pragma unroll
                for (int j = 0; j < 8; j++) {
                    float m = fmaxf(E1v * ev[j], F1v * fv[j]);   // exp(leakyrelu(f1+f2))
                    pv[j] = ((bits8 >> j) & 1u) ? m : 0.f;
                }
#pragma unroll
                for (int i = 0; i < 4; i++) af[k0].u[i] = pkbf(pv[2 * i], pv[2 * i + 1]);
            }
#pragma unroll
            for (int k0 = 0; k0 < 2; k0++) {
                short8 bb0 = ld_bf8(&Bsub[(0 * 16 + p) * 72 + q * 8 + k0 * 32]);
                short8 bb1 = ld_bf8(&Bsub[(1 * 16 + p) * 72 + q * 8 + k0 * 32]);
                short8 bb2 = ld_bf8(&Bsub[(2 * 16 + p) * 72 + q * 8 + k0 * 32]);
                short8 bb3 = ld_bf8(&Bsub[(3 * 16 + p) * 72 + q * 8 + k0 * 32]);
                accL   = __builtin_amdgcn_mfma_f32_16x16x32_bf16(af[k0].s, ones, accL, 0, 0, 0);
                acc[0] = __builtin_amdgcn_mfma_f32_16x16x32_bf16(af[k0].s, bb0, acc[0], 0, 0, 0);
                acc[1] = __builtin_amdgcn_mfma_f32_16x16x32_bf16(af[k0].s, bb1, acc[1], 0, 0, 0);
                acc[2] = __builtin_amdgcn_mfma_f32_16x16x32_bf16(af[k0].s, bb2, acc[2], 0, 0, 0);
                acc[3] = __builtin_amdgcn_mfma_f32_16x16x32_bf16(af[k0].s, bb3, acc[3], 0, 0, 0);
            }
        }
        if (it + 1 < 16) {
            *(uint4*)&Bh[cur ^ 1][sr * 72 + sc]               = na0;
            *(uint4*)&Bh[cur ^ 1][sr * 72 + sc + 8]           = na1;
            *(uint4*)&Bh[cur ^ 1][64 * 72 + sr * 72 + sc]     = nb0;
            *(uint4*)&Bh[cur ^ 1][64 * 72 + sr * 72 + sc + 8] = nb1;
            wrd[0] = nw0;
            wrd[1] = nw1;
        }
    }
    if (p == 0) {
#pragma unroll
        for (int reg = 0; reg < 4; reg++)
            Lpart[((size_t)z * 8 + h) * N_ + n0 + w * 16 + q * 4 + reg] = accL[reg];
    }
    float* dst = (z == 0) ? out : opart;
#pragma unroll
    for (int ct = 0; ct < 4; ct++)
#pragma unroll
        for (int reg = 0; reg < 4; reg++) {
            int rr = w * 16 + q * 4 + reg;
            dst[(size_t)(n0 + rr) * (H_ * OUT_) + h * OUT_ + ct * 16 + p] = acc[ct][reg];
        }
}

// ---------- combine z=1 partial + normalize
__global__ __launch_bounds__(256) void combine(float* __restrict__ outb,
                                               const float* __restrict__ opart,
                                               const float* __restrict__ Lpart) {
    size_t g = (size_t)blockIdx.x * 256 + threadIdx.x;   // float4 index
    int n = (int)(g >> 7);
    int c = (int)(g & 127);
    int h = c >> 4;
    float4 o0 = ((const float4*)outb)[g];
    float4 o1 = ((const float4*)opart)[g];
    float L = Lpart[(size_t)h * N_ + n] + Lpart[(size_t)(8 + h) * N_ + n];
    float inv = 1.f / L;
    ((float4*)outb)[g] = make_float4((o0.x + o1.x) * inv, (o0.y + o1.y) * inv,
                                     (o0.z + o1.z) * inv, (o0.w + o1.w) * inv);
}

extern "C" void kernel_launch(void* const* d_in, const int* in_sizes, int n_in,
                              void* d_out, int out_size, void* d_ws, size_t ws_size,
                              hipStream_t stream) {
    const float* x   = nullptr;
    const int*   adj = nullptr;
    const float* W   = nullptr;
    const float* a1  = nullptr;
    const float* a2  = nullptr;
    for (int i = 0; i < n_in; i++) {
        long long sz = in_sizes[i];
        if      (sz == (long long)N_ * IN_)        x   = (const float*)d_in[i];
        else if (sz == (long long)N_ * N_)         adj = (const int*)d_in[i];
        else if (sz == (long long)H_ * IN_ * OUT_) W   = (const float*)d_in[i];
        else if (sz == (long long)H_ * OUT_) {
            if (!a1) a1 = (const float*)d_in[i];
            else     a2 = (const float*)d_in[i];
        }
    }
    if (!x)   x   = (const float*)d_in[0];
    if (!adj) adj = (const int*)d_in[1];
    if (!W)   W   = (const float*)d_in[2];
    if (!a1)  a1  = (const float*)d_in[3];
    if (!a2)  a2  = (const float*)d_in[4];
    float* out = (float*)d_out;

    char* ws = (char*)d_ws;
    unsigned long long* bitsT = (unsigned long long*)ws;             // 2 MB @0
    uint16_t* WhhT = (uint16_t*)(ws + (2u << 20));                   // 4 MB
    uint16_t* WTh  = (uint16_t*)(ws + (6u << 20));                   // 512 KB
    uint16_t* WTl  = (uint16_t*)(ws + (6u << 20) + (512u << 10));    // 512 KB
    float2* EF1    = (float2*)  (ws + (7u << 20));                   // 256 KB
    float2* EF2    = (float2*)  (ws + (7u << 20) + (256u << 10));    // 256 KB
    float* Lpart   = (float*)   (ws + (7u << 20) + (512u << 10));    // 512 KB (uses 256K)
    float* opart   = (float*)   (ws + (8u << 20));                   // 8 MB

    split_wT<<<dim3(IN_ / 64, H_), 256, 0, stream>>>(W, WTh, WTl);
    fused_prep<<<PACKB_ + (N_ / 32) * H_, 256, 0, stream>>>(adj, x, WTh, WTl, a1, a2,
                                                            bitsT, WhhT, EF1, EF2);
    gat_main<<<dim3(N_ / 64, H_, 2), 256, 0, stream>>>(bitsT, WhhT, EF1, EF2, out, opart, Lpart);
    combine<<<(N_ * H_ * OUT_) / (256 * 4), 256, 0, stream>>>(out, opart, Lpart);
}